// Round 1
// baseline (269.109 us; speedup 1.0000x reference)
//
#include <hip/hip_runtime.h>
#include <math.h>

#define N 4096
#define H 64
#define MAXDEG 128
#define NEG_SLOPE 0.2f
#define LN_EPS 1e-5f

__device__ __forceinline__ float wave_reduce_sum(float v) {
    #pragma unroll
    for (int m = 32; m >= 1; m >>= 1) v += __shfl_xor(v, m, 64);
    return v;
}
__device__ __forceinline__ float wave_reduce_max(float v) {
    #pragma unroll
    for (int m = 32; m >= 1; m >>= 1) v = fmaxf(v, __shfl_xor(v, m, 64));
    return v;
}

// Build neighbor lists: dest i's neighbors are {j : adj[j][i] != 0} U {i}.
// Thread t handles column i = t & (N-1), row-chunk = t >> 12 (64 rows each).
// Coalesced: within a wave, 64 consecutive i at fixed j -> 256B contiguous.
__global__ void build_nbr(const float* __restrict__ adj,
                          int* __restrict__ cnt, int* __restrict__ nbr) {
    int t = blockIdx.x * blockDim.x + threadIdx.x;
    int i = t & (N - 1);
    int j0 = (t >> 12) * 64;
    for (int jj = 0; jj < 64; ++jj) {
        int j = j0 + jj;
        float a = adj[(size_t)j * N + i];
        if (a != 0.0f || j == i) {
            int p = atomicAdd(&cnt[i], 1);
            if (p < MAXDEG) nbr[i * MAXDEG + p] = j;
        }
    }
}

// x = (feat @ w1 + b1) @ w2 + b2 ; h = x.  Wave per row, lane = feature col.
__global__ void emb_kernel(const int* __restrict__ timestep,
                           const float* __restrict__ arr, const float* __restrict__ dep,
                           const float* __restrict__ hard,
                           const float* __restrict__ w1, const float* __restrict__ b1,
                           const float* __restrict__ w2, const float* __restrict__ b2,
                           float* __restrict__ x, float* __restrict__ h) {
    int wave = threadIdx.x >> 6;
    int lane = threadIdx.x & 63;
    int i = blockIdx.x * 4 + wave;
    float ts = (float)(*timestep);
    float pr = (ts - arr[i]) / (dep[i] - arr[i]);
    float hd = hard[i];
    float t = pr * w1[lane] + hd * w1[64 + lane] + b1[lane];
    float acc = b2[lane];
    #pragma unroll
    for (int k = 0; k < 64; ++k)
        acc += __shfl(t, k, 64) * w2[k * 64 + lane];
    x[i * 64 + lane] = acc;
    h[i * 64 + lane] = acc;
}

// hw = h @ W ; ssrc = hw . asrc ; sdst = hw . adst.  Wave per row.
__global__ void gat_transform(const float* __restrict__ h, const float* __restrict__ W,
                              const float* __restrict__ asrc, const float* __restrict__ adst,
                              float* __restrict__ hw, float* __restrict__ ssrc,
                              float* __restrict__ sdst) {
    int wave = threadIdx.x >> 6;
    int lane = threadIdx.x & 63;
    int i = blockIdx.x * 4 + wave;
    float r = h[i * 64 + lane];
    float acc = 0.f;
    #pragma unroll
    for (int k = 0; k < 64; ++k)
        acc += __shfl(r, k, 64) * W[k * 64 + lane];
    hw[i * 64 + lane] = acc;
    float s1 = wave_reduce_sum(acc * asrc[lane]);
    float s2 = wave_reduce_sum(acc * adst[lane]);
    if (lane == 0) { ssrc[i] = s1; sdst[i] = s2; }
}

// h_out[i] = softmax_j(leaky(ssrc[j]+sdst[i])) @ hw + b ; optional relu.
__global__ void gat_aggregate(const float* __restrict__ hw, const float* __restrict__ ssrc,
                              const float* __restrict__ sdst, const int* __restrict__ nbr,
                              const int* __restrict__ cnt, const float* __restrict__ b,
                              float* __restrict__ hout, int do_relu) {
    __shared__ float p_lds[4][MAXDEG];
    int wave = threadIdx.x >> 6;
    int lane = threadIdx.x & 63;
    int i = blockIdx.x * 4 + wave;
    int deg = min(cnt[i], MAXDEG);
    float sd = sdst[i];
    float e0 = -1e30f, e1 = -1e30f;
    if (lane < deg) {
        int j = nbr[i * MAXDEG + lane];
        float v = ssrc[j] + sd;
        e0 = v > 0.f ? v : NEG_SLOPE * v;
    }
    if (lane + 64 < deg) {
        int j = nbr[i * MAXDEG + lane + 64];
        float v = ssrc[j] + sd;
        e1 = v > 0.f ? v : NEG_SLOPE * v;
    }
    float m = wave_reduce_max(fmaxf(e0, e1));
    float p0 = (lane < deg) ? expf(e0 - m) : 0.f;
    float p1 = (lane + 64 < deg) ? expf(e1 - m) : 0.f;
    float Z = wave_reduce_sum(p0 + p1);
    p_lds[wave][lane] = p0;
    p_lds[wave][lane + 64] = p1;
    __syncthreads();
    float acc = 0.f;
    for (int n = 0; n < deg; ++n) {
        int j = nbr[i * MAXDEG + n];        // wave-uniform scalar load
        acc += p_lds[wave][n] * hw[j * 64 + lane];  // coalesced row gather
    }
    acc = acc / Z + b[lane];
    if (do_relu) acc = fmaxf(acc, 0.f);
    hout[i * 64 + lane] = acc;
}

// residual + layernorm + (ln_x . val_w) accumulated across rows.
__global__ void finalize_kernel(const float* __restrict__ x, const float* __restrict__ h,
                                const float* __restrict__ vw, float* __restrict__ accum) {
    int wave = threadIdx.x >> 6;
    int lane = threadIdx.x & 63;
    int i = blockIdx.x * 4 + wave;
    float v = x[i * 64 + lane] + h[i * 64 + lane];
    float mu = wave_reduce_sum(v) * (1.f / 64.f);
    float d = v - mu;
    float var = wave_reduce_sum(d * d) * (1.f / 64.f);
    float ln = d * rsqrtf(var + LN_EPS);
    float part = wave_reduce_sum(ln * vw[lane]);
    if (lane == 0) atomicAdd(accum, part);
}

__global__ void out_kernel(const float* __restrict__ accum,
                           const float* __restrict__ val_b, float* __restrict__ out) {
    float v = accum[0] * (1.f / (float)N) + val_b[0];
    out[0] = fmaxf(v, 0.f);
}

extern "C" void kernel_launch(void* const* d_in, const int* in_sizes, int n_in,
                              void* d_out, int out_size, void* d_ws, size_t ws_size,
                              hipStream_t stream) {
    const float* adj        = (const float*)d_in[0];
    const int*   timestep   = (const int*)  d_in[1];
    const float* arrivals   = (const float*)d_in[2];
    const float* departures = (const float*)d_in[3];
    const float* hard       = (const float*)d_in[4];
    // d_in[5] active_agents: unused by reference
    const float* emb_w1     = (const float*)d_in[6];
    const float* emb_b1     = (const float*)d_in[7];
    const float* emb_w2     = (const float*)d_in[8];
    const float* emb_b2     = (const float*)d_in[9];
    const float* gat_w      = (const float*)d_in[10];
    const float* gat_asrc   = (const float*)d_in[11];
    const float* gat_adst   = (const float*)d_in[12];
    const float* gat_b      = (const float*)d_in[13];
    const float* val_w      = (const float*)d_in[14];
    const float* val_b      = (const float*)d_in[15];

    char* ws = (char*)d_ws;
    int*   cnt   = (int*)  (ws);                    // 16 KB
    float* accum = (float*)(ws + 16384);            // 16 B
    int*   nbr   = (int*)  (ws + 65536);            // 2 MB
    float* x     = (float*)(ws + (4u << 20));       // 1 MB
    float* h     = (float*)(ws + (5u << 20));       // 1 MB
    float* hw    = (float*)(ws + (6u << 20));       // 1 MB
    float* ssrc  = (float*)(ws + (7u << 20));       // 16 KB
    float* sdst  = (float*)(ws + (7u << 20) + 65536);

    hipMemsetAsync(ws, 0, 16384 + 64, stream);      // zero cnt + accum

    build_nbr<<<N * 64 / 256, 256, 0, stream>>>(adj, cnt, nbr);
    emb_kernel<<<N / 4, 256, 0, stream>>>(timestep, arrivals, departures, hard,
                                          emb_w1, emb_b1, emb_w2, emb_b2, x, h);
    for (int l = 0; l < 3; ++l) {
        gat_transform<<<N / 4, 256, 0, stream>>>(h, gat_w + l * 64 * 64,
                                                 gat_asrc + l * 64, gat_adst + l * 64,
                                                 hw, ssrc, sdst);
        gat_aggregate<<<N / 4, 256, 0, stream>>>(hw, ssrc, sdst, nbr, cnt,
                                                 gat_b + l * 64, h, (l < 2) ? 1 : 0);
    }
    finalize_kernel<<<N / 4, 256, 0, stream>>>(x, h, val_w, accum);
    out_kernel<<<1, 1, 0, stream>>>(accum, val_b, (float*)d_out);
}